// Round 4
// baseline (264.844 us; speedup 1.0000x reference)
//
#include <hip/hip_runtime.h>
#include <stdint.h>

constexpr int B = 4, C = 128, H = 256, W = 512;
constexpr int HW = H * W;

constexpr int TW = 64, TH = 16;        // pixel tile per block
constexpr int HALO = 8;                // covers |flow| <= ~8 px; else global fallback
constexpr int SH = TH + 2 * HALO + 2;  // 34 staged rows
constexpr int SW = TW + 2 * HALO + 2;  // 82 staged cols
constexpr int SN = SH * SW;            // 2788 floats
constexpr int NCHUNK = 11;             // ceil(SN/256)
constexpr int SNP = NCHUNK * 256;      // 2816 (padded: DMA chunks are full waves)
constexpr int CPG = 32;                // channels per block (grid.y = 4)

__device__ __forceinline__ void load_lds4(const float* g, float* l) {
  // 4B per lane, LDS dest = wave-uniform base + lane*4 (linear)
  __builtin_amdgcn_global_load_lds(
      (__attribute__((address_space(1))) void*)g,
      (__attribute__((address_space(3))) void*)l, 4, 0, 0);
}

__global__ __launch_bounds__(256) void warp_flow_kernel(
    const float* __restrict__ x, const float* __restrict__ flow,
    float* __restrict__ out) {
  __shared__ float sm[SNP];

  // XCD-contiguous swizzle over 512 tiles (8 XCDs round-robin dispatch)
  const int orig = blockIdx.x;
  const int swz = ((orig & 7) << 6) | (orig >> 3);  // bijective on [0,512)

  const int b = swz >> 7;
  const int tid = swz & 127;
  const int r0 = (tid >> 3) * TH;
  const int c0 = (tid & 7) * TW;
  const int cg0 = blockIdx.y * CPG;

  const int t = threadIdx.x;
  const int lw = t & 63;
  const int lr = t >> 6;

  // ---- per-pixel precompute (4 px/thread), channel-invariant ----
  float wa0[4], wb0[4], wa1[4], wb1[4];  // folded pair-weights (row0, row1)
  int ob0[4], ob1[4], pout[4];           // LDS elem offsets (or global offs if fb)
  unsigned fb = 0;

#pragma unroll
  for (int k = 0; k < 4; ++k) {
    const int h = r0 + lr + 4 * k;
    const int w = c0 + lw;

    const int fidx = ((b * 2) * H + h) * W + w;
    const float flx = flow[fidx];
    const float fly = flow[fidx + HW];

    // replicate reference arithmetic (fp32, align_corners=True round trip)
    const float gx = (-1.0f + 2.0f * (float)w / (float)(W - 1)) + flx * 2.0f / (float)(W - 1);
    const float gy = (-1.0f + 2.0f * (float)h / (float)(H - 1)) + fly * 2.0f / (float)(H - 1);
    const float fx = (gx + 1.0f) * 0.5f * (float)(W - 1);
    const float fy = (gy + 1.0f) * 0.5f * (float)(H - 1);

    const float x0f = floorf(fx), y0f = floorf(fy);
    const float x1f = x0f + 1.0f, y1f = y0f + 1.0f;
    const float wx1 = fx - x0f, wx0 = 1.0f - wx1;
    const float wy1 = fy - y0f, wy0 = 1.0f - wy1;

    const bool vx0 = (x0f >= 0.0f) && (x0f <= (float)(W - 1));
    const bool vx1 = (x1f >= 0.0f) && (x1f <= (float)(W - 1));
    const bool vy0 = (y0f >= 0.0f) && (y0f <= (float)(H - 1));
    const bool vy1 = (y1f >= 0.0f) && (y1f <= (float)(H - 1));

    float a00 = wx0 * wy0 * ((vx0 && vy0) ? 1.0f : 0.0f);
    float a10 = wx1 * wy0 * ((vx1 && vy0) ? 1.0f : 0.0f);
    float a01 = wx0 * wy1 * ((vx0 && vy1) ? 1.0f : 0.0f);
    float a11 = wx1 * wy1 * ((vx1 && vy1) ? 1.0f : 0.0f);

    const float msum = a00 + a10 + a01 + a11;
    const float mask = (msum >= 0.9999f) ? 1.0f : 0.0f;
    a00 *= mask; a10 *= mask; a01 *= mask; a11 *= mask;

    const int ix0 = min(max((int)x0f, 0), W - 1);
    const int ix1 = min(max((int)x1f, 0), W - 1);
    const int iy0 = min(max((int)y0f, 0), H - 1);
    const int iy1 = min(max((int)y1f, 0), H - 1);

    // pair base column: read cols (bx, bx+1); route weights by d0/d1
    const int bx = min(ix0, W - 2);
    const int d0 = ix0 - bx;  // 0 or 1
    const int d1 = ix1 - bx;  // 0 or 1
    wa0[k] = (d0 ? 0.0f : a00) + (d1 ? 0.0f : a10);
    wb0[k] = (d0 ? a00 : 0.0f) + (d1 ? a10 : 0.0f);
    wa1[k] = (d0 ? 0.0f : a01) + (d1 ? 0.0f : a11);
    wb1[k] = (d0 ? a01 : 0.0f) + (d1 ? a11 : 0.0f);

    const int lbx = bx - (c0 - HALO);
    const int l0y = iy0 - (r0 - HALO);
    const int l1y = iy1 - (r0 - HALO);
    const bool intile = (lbx >= 0) & (lbx + 1 < SW) & (l0y >= 0) & (l1y < SH);

    if (intile) {
      ob0[k] = l0y * SW + lbx;
      ob1[k] = l1y * SW + lbx;
    } else {
      ob0[k] = iy0 * W + bx;  // global fallback (bx+1 <= W-1 in-bounds)
      ob1[k] = iy1 * W + bx;
      fb |= (1u << k);
    }
    pout[k] = h * W + w;
  }

  // staging source offsets (channel-invariant); chunks are full 256-thread waves
  int soff[NCHUNK];
#pragma unroll
  for (int i = 0; i < NCHUNK; ++i) {
    const int s = t + 256 * i;
    const int vr = s / SW;  // may exceed SH-1 in pad region -> clamp keeps it legal
    const int vc = s - vr * SW;
    const int grow = min(max(r0 - HALO + vr, 0), H - 1);
    const int gcol = min(max(c0 - HALO + vc, 0), W - 1);
    soff[i] = grow * W + gcol;
  }
  const int wbase = (t >> 6) * 64;  // wave-uniform LDS base

  // ---- channel loop: DMA-stage tile -> sample from LDS ----
  for (int c = cg0; c < cg0 + CPG; ++c) {
    const float* __restrict__ xp = x + ((size_t)b * C + c) * HW;
    float* __restrict__ op = out + ((size_t)b * C + c) * HW;

#pragma unroll
    for (int i = 0; i < NCHUNK; ++i) {
      load_lds4(xp + soff[i], &sm[wbase + i * 256]);
    }
    __syncthreads();  // drains vmcnt(0): DMA landed

#pragma unroll
    for (int k = 0; k < 4; ++k) {
      float e00, e01, e10, e11;
      if (!((fb >> k) & 1u)) {
        e00 = sm[ob0[k]]; e01 = sm[ob0[k] + 1];   // -> ds_read2_b32
        e10 = sm[ob1[k]]; e11 = sm[ob1[k] + 1];
      } else {  // rare: displacement beyond halo
        e00 = xp[ob0[k]]; e01 = xp[ob0[k] + 1];
        e10 = xp[ob1[k]]; e11 = xp[ob1[k] + 1];
      }
      const float r = wa0[k] * e00 + wb0[k] * e01 + wa1[k] * e10 + wb1[k] * e11;
      __builtin_nontemporal_store(r, &op[pout[k]]);
    }
    __syncthreads();  // all reads done before next channel's DMA overwrites
  }
}

extern "C" void kernel_launch(void* const* d_in, const int* in_sizes, int n_in,
                              void* d_out, int out_size, void* d_ws, size_t ws_size,
                              hipStream_t stream) {
  const float* x = (const float*)d_in[0];
  const float* flow = (const float*)d_in[1];
  float* out = (float*)d_out;
  dim3 grid((H / TH) * (W / TW) * B, C / CPG);  // (512, 4)
  warp_flow_kernel<<<grid, dim3(256), 0, stream>>>(x, flow, out);
}

// Round 5
// 233.091 us; speedup vs baseline: 1.1362x; 1.1362x over previous
//
#include <hip/hip_runtime.h>
#include <stdint.h>

constexpr int B = 4, C = 128, H = 256, W = 512;
constexpr int HW = H * W;
constexpr int CHW = C * HW;

constexpr int TW = 64, TH = 16;        // pixel tile per block
constexpr int HALO = 8;                // covers |flow| <= ~8 px; else global fallback
constexpr int SH = TH + 2 * HALO + 2;  // 34 staged rows
constexpr int SW2 = 88;                // staged row width (22 lanes x 4 floats)
constexpr int LPR = 22;                // 16B lane-slots per row
constexpr int SLOTS = SH * LPR;        // 748 slots
constexpr int NCH = 3;                 // ceil(748/256) DMA chunks (256 slots each)
constexpr int SFL = NCH * 1024;        // 3072 floats per channel buffer (12 KB)
constexpr int CPG = 32;                // channels per block (grid.y = 4)

__device__ __forceinline__ void load_lds16(const float* g, float* l) {
  // 16B per lane; LDS dest = wave-uniform base + lane*16 (linear)
  __builtin_amdgcn_global_load_lds(
      (__attribute__((address_space(1))) void*)g,
      (__attribute__((address_space(3))) void*)l, 16, 0, 0);
}

__global__ __launch_bounds__(256) void warp_flow_kernel(
    const float* __restrict__ x, const float* __restrict__ flow,
    float* __restrict__ out) {
  __shared__ float sm[2][SFL];  // 24 KB total -> 6 blocks/CU

  // XCD-contiguous swizzle over 512 tiles (8 XCDs, round-robin dispatch)
  const int orig = blockIdx.x;
  const int swz = ((orig & 7) << 6) | (orig >> 3);  // bijective on [0,512)

  const int b = swz >> 7;
  const int tid = swz & 127;
  const int r0 = (tid >> 3) * TH;
  const int c0 = (tid & 7) * TW;
  const int cg0 = blockIdx.y * CPG;

  const int t = threadIdx.x;
  const int lw = t & 63;
  const int lr = t >> 6;

  // ---- per-pixel precompute (4 px/thread), channel-invariant ----
  float wa0[4], wb0[4], wa1[4], wb1[4];
  int ob0[4], ob1[4], pout[4];  // LDS elem offsets, or global plane offsets if fb
  unsigned fb = 0;

#pragma unroll
  for (int k = 0; k < 4; ++k) {
    const int h = r0 + lr + 4 * k;
    const int w = c0 + lw;

    const int fidx = ((b * 2) * H + h) * W + w;
    const float flx = flow[fidx];
    const float fly = flow[fidx + HW];

    // replicate reference arithmetic (fp32, align_corners=True round trip)
    const float gx = (-1.0f + 2.0f * (float)w / (float)(W - 1)) + flx * 2.0f / (float)(W - 1);
    const float gy = (-1.0f + 2.0f * (float)h / (float)(H - 1)) + fly * 2.0f / (float)(H - 1);
    const float fx = (gx + 1.0f) * 0.5f * (float)(W - 1);
    const float fy = (gy + 1.0f) * 0.5f * (float)(H - 1);

    const float x0f = floorf(fx), y0f = floorf(fy);
    const float x1f = x0f + 1.0f, y1f = y0f + 1.0f;
    const float wx1 = fx - x0f, wx0 = 1.0f - wx1;
    const float wy1 = fy - y0f, wy0 = 1.0f - wy1;

    const bool vx0 = (x0f >= 0.0f) && (x0f <= (float)(W - 1));
    const bool vx1 = (x1f >= 0.0f) && (x1f <= (float)(W - 1));
    const bool vy0 = (y0f >= 0.0f) && (y0f <= (float)(H - 1));
    const bool vy1 = (y1f >= 0.0f) && (y1f <= (float)(H - 1));

    float a00 = wx0 * wy0 * ((vx0 && vy0) ? 1.0f : 0.0f);
    float a10 = wx1 * wy0 * ((vx1 && vy0) ? 1.0f : 0.0f);
    float a01 = wx0 * wy1 * ((vx0 && vy1) ? 1.0f : 0.0f);
    float a11 = wx1 * wy1 * ((vx1 && vy1) ? 1.0f : 0.0f);

    const float msum = a00 + a10 + a01 + a11;
    const float mask = (msum >= 0.9999f) ? 1.0f : 0.0f;
    a00 *= mask; a10 *= mask; a01 *= mask; a11 *= mask;

    const int ix0 = min(max((int)x0f, 0), W - 1);
    const int ix1 = min(max((int)x1f, 0), W - 1);
    const int iy0 = min(max((int)y0f, 0), H - 1);
    const int iy1 = min(max((int)y1f, 0), H - 1);

    // paired columns (bx, bx+1); fold corner routing into weights
    const int bx = min(ix0, W - 2);
    const int d0 = ix0 - bx;
    const int d1 = ix1 - bx;
    wa0[k] = (d0 ? 0.0f : a00) + (d1 ? 0.0f : a10);
    wb0[k] = (d0 ? a00 : 0.0f) + (d1 ? a10 : 0.0f);
    wa1[k] = (d0 ? 0.0f : a01) + (d1 ? 0.0f : a11);
    wb1[k] = (d0 ? a01 : 0.0f) + (d1 ? a11 : 0.0f);

    const int lbx = bx - (c0 - HALO);
    const int l0y = iy0 - (r0 - HALO);
    const int l1y = iy1 - (r0 - HALO);
    const bool intile = (lbx >= 0) & (lbx + 1 < SW2) & (l0y >= 0) & (l1y < SH);

    if (intile) {
      ob0[k] = l0y * SW2 + lbx;
      ob1[k] = l1y * SW2 + lbx;
    } else {
      ob0[k] = iy0 * W + bx;  // global fallback (bx+1 <= W-1)
      ob1[k] = iy1 * W + bx;
      fb |= (1u << k);
    }
    pout[k] = h * W + w;
  }

  // staging source offsets (channel-invariant part), 16B-aligned, may be OOB
  // (clamped at use; clamped slots are never consumed)
  int flat[NCH];
#pragma unroll
  for (int j = 0; j < NCH; ++j) {
    const int s = t + 256 * j;
    const int vr = s / LPR;
    const int vc4 = (s - vr * LPR) * 4;
    flat[j] = (r0 - HALO + vr) * W + (c0 - HALO + vc4);
  }
  const int wvbase = (t >> 6) * 256;  // wave-uniform float offset within chunk
  const float* __restrict__ xb = x + (size_t)b * CHW;

  // ---- prologue: stage first channel into buf 0 ----
  {
    const int cHW = cg0 * HW;
#pragma unroll
    for (int j = 0; j < NCH; ++j) {
      const int off = min(max(flat[j] + cHW, 0), CHW - 4);
      load_lds16(xb + off, &sm[0][j * 1024 + wvbase]);
    }
  }

  // ---- pipelined channel loop: counted vmcnt, raw barriers ----
  for (int i = 0; i < CPG; ++i) {
    const int c = cg0 + i;
    const int cur = i & 1;

    if (i + 1 < CPG) {
      const int cHW = (c + 1) * HW;
#pragma unroll
      for (int j = 0; j < NCH; ++j) {
        const int off = min(max(flat[j] + cHW, 0), CHW - 4);
        load_lds16(xb + off, &sm[cur ^ 1][j * 1024 + wvbase]);
      }
      if (i == 0) {
        asm volatile("s_waitcnt vmcnt(3)" ::: "memory");  // drain ch0 DMA
      } else {
        asm volatile("s_waitcnt vmcnt(7)" ::: "memory");  // 4 stores + 3 new DMA
      }
    } else {
      asm volatile("s_waitcnt vmcnt(4)" ::: "memory");  // 4 stores outstanding
    }
    __builtin_amdgcn_sched_barrier(0);
    __builtin_amdgcn_s_barrier();  // buf[cur] staged for all waves

    const float* __restrict__ xp = xb + (size_t)c * HW;
    float* __restrict__ op = out + ((size_t)b * C + c) * HW;
    const float* __restrict__ sp = sm[cur];

#pragma unroll
    for (int k = 0; k < 4; ++k) {
      float e00, e01, e10, e11;
      if (!((fb >> k) & 1u)) {
        e00 = sp[ob0[k]]; e01 = sp[ob0[k] + 1];  // ds_read2_b32
        e10 = sp[ob1[k]]; e11 = sp[ob1[k] + 1];
      } else {  // rare: displacement beyond halo
        e00 = xp[ob0[k]]; e01 = xp[ob0[k] + 1];
        e10 = xp[ob1[k]]; e11 = xp[ob1[k] + 1];
      }
      const float r = wa0[k] * e00 + wb0[k] * e01 + wa1[k] * e10 + wb1[k] * e11;
      __builtin_nontemporal_store(r, &op[pout[k]]);
    }
    __builtin_amdgcn_s_barrier();  // all reads of buf[cur] done -> may overwrite
  }
}

extern "C" void kernel_launch(void* const* d_in, const int* in_sizes, int n_in,
                              void* d_out, int out_size, void* d_ws, size_t ws_size,
                              hipStream_t stream) {
  const float* x = (const float*)d_in[0];
  const float* flow = (const float*)d_in[1];
  float* out = (float*)d_out;
  dim3 grid((H / TH) * (W / TW) * B, C / CPG);  // (512, 4)
  warp_flow_kernel<<<grid, dim3(256), 0, stream>>>(x, flow, out);
}

// Round 6
// 177.574 us; speedup vs baseline: 1.4915x; 1.3126x over previous
//
#include <hip/hip_runtime.h>

constexpr int B = 4, C = 128, H = 256, W = 512;
constexpr int HW = H * W;
constexpr int CPB = 32;  // channels per blockIdx.y slice (grid.y = 4)

typedef float f2 __attribute__((ext_vector_type(2), aligned(4)));

__global__ __launch_bounds__(256) void warp_flow_kernel(
    const float* __restrict__ x, const float* __restrict__ flow,
    float* __restrict__ out) {
  // XCD-aware swizzle: XCD k owns 256 contiguous blocks = 128 contiguous
  // image rows -> each x row fetched by exactly one XCD L2 (R2: 570->143MB).
  const int orig = blockIdx.x;
  const int swz = ((orig & 7) << 8) | (orig >> 3);  // bijective on [0,2048)

  const int pid = swz * 256 + threadIdx.x;  // [0, B*H*W)
  const int w = pid & (W - 1);
  const int h = (pid >> 9) & (H - 1);
  const int b = pid >> 17;

  // flow layout [B,2,H,W]
  const int fidx = ((b * 2) * H + h) * W + w;
  const float flx = flow[fidx];
  const float fly = flow[fidx + HW];

  // replicate reference arithmetic (fp32, align_corners=True round trip)
  const float gx = (-1.0f + 2.0f * (float)w / (float)(W - 1)) + flx * 2.0f / (float)(W - 1);
  const float gy = (-1.0f + 2.0f * (float)h / (float)(H - 1)) + fly * 2.0f / (float)(H - 1);
  const float fx = (gx + 1.0f) * 0.5f * (float)(W - 1);
  const float fy = (gy + 1.0f) * 0.5f * (float)(H - 1);

  const float x0f = floorf(fx), y0f = floorf(fy);
  const float x1f = x0f + 1.0f, y1f = y0f + 1.0f;
  const float wx1 = fx - x0f, wx0 = 1.0f - wx1;
  const float wy1 = fy - y0f, wy0 = 1.0f - wy1;

  const bool vx0 = (x0f >= 0.0f) && (x0f <= (float)(W - 1));
  const bool vx1 = (x1f >= 0.0f) && (x1f <= (float)(W - 1));
  const bool vy0 = (y0f >= 0.0f) && (y0f <= (float)(H - 1));
  const bool vy1 = (y1f >= 0.0f) && (y1f <= (float)(H - 1));

  float a00 = wx0 * wy0 * ((vx0 && vy0) ? 1.0f : 0.0f);
  float a10 = wx1 * wy0 * ((vx1 && vy0) ? 1.0f : 0.0f);
  float a01 = wx0 * wy1 * ((vx0 && vy1) ? 1.0f : 0.0f);
  float a11 = wx1 * wy1 * ((vx1 && vy1) ? 1.0f : 0.0f);

  const float msum = a00 + a10 + a01 + a11;
  const float mask = (msum >= 0.9999f) ? 1.0f : 0.0f;
  a00 *= mask; a10 *= mask; a01 *= mask; a11 *= mask;

  const int ix0 = min(max((int)x0f, 0), W - 1);
  const int ix1 = min(max((int)x1f, 0), W - 1);
  const int iy0 = min(max((int)y0f, 0), H - 1);
  const int iy1 = min(max((int)y1f, 0), H - 1);

  // fold column clamp into pair weights: read cols (bx, bx+1), route by d0/d1
  const int bx = min(ix0, W - 2);
  const int d0 = ix0 - bx;  // 0 or 1
  const int d1 = ix1 - bx;  // 0 or 1
  const float wa0 = (d0 ? 0.0f : a00) + (d1 ? 0.0f : a10);
  const float wb0 = (d0 ? a00 : 0.0f) + (d1 ? a10 : 0.0f);
  const float wa1 = (d0 ? 0.0f : a01) + (d1 ? 0.0f : a11);
  const float wb1 = (d0 ? a01 : 0.0f) + (d1 ? a11 : 0.0f);

  const int o0 = iy0 * W + bx;  // row-y0 pair base (in-bounds: bx+1 <= W-1)
  const int o1 = iy1 * W + bx;  // row-y1 pair base

  const int cg0 = blockIdx.y * CPB;
  const float* __restrict__ xp = x + ((size_t)b * C + cg0) * HW;
  float* __restrict__ op = out + ((size_t)b * C + cg0) * HW + h * W + w;

#pragma unroll 8
  for (int c = 0; c < CPB; ++c) {
    const int coff = c * HW;
    const f2 va = *reinterpret_cast<const f2*>(xp + coff + o0);  // dwordx2
    const f2 vb = *reinterpret_cast<const f2*>(xp + coff + o1);  // dwordx2
    const float r = wa0 * va[0] + wb0 * va[1] + wa1 * vb[0] + wb1 * vb[1];
    __builtin_nontemporal_store(r, op + coff);
  }
}

extern "C" void kernel_launch(void* const* d_in, const int* in_sizes, int n_in,
                              void* d_out, int out_size, void* d_ws, size_t ws_size,
                              hipStream_t stream) {
  const float* x = (const float*)d_in[0];
  const float* flow = (const float*)d_in[1];
  float* out = (float*)d_out;
  const int npix = B * H * W;                 // 524288
  dim3 grid(npix / 256, C / CPB);             // (2048, 4)
  warp_flow_kernel<<<grid, dim3(256), 0, stream>>>(x, flow, out);
}